// Round 1
// 64.319 us; speedup vs baseline: 1.0055x; 1.0055x over previous
//
#include <hip/hip_runtime.h>
#include <math.h>

// Kendall's Tau loss, n=8192 fp32.
// disc = #{(i,j): (p_i<p_j) != (t_i<t_j)} over ordered pairs (i != j; i==j
// contributes 0 naturally). sum S = n(n-1) - 2*disc; loss = 2*disc/(n(n-1)).
// Integer-exact. 1024 blocks (4/CU, 4 waves/SIMD), IPT=8 register blocking,
// wave-uniform ds_read_b128 j-tile broadcast (2 j's per read), fully static
// inner loop: tails handled by +INF padding ((inf<x)==(inf<y)==false -> 0).

constexpr int BLK = 256;       // threads per block
constexpr int IPT = 8;         // i's per thread (independent acc chains)
constexpr int TI  = BLK * IPT; // 2048 i's per block
constexpr int TJ  = 32;        // j's per block tile (256 B LDS)

__global__ __launch_bounds__(BLK) void ktau_pairs(
    const float* __restrict__ p, const float* __restrict__ t,
    int* __restrict__ partial, int n) {
  __shared__ __align__(16) float2 jv[TJ];
  const int tid = threadIdx.x;
  const int i0  = blockIdx.x * TI;
  const int j0  = blockIdx.y * TJ;

  if (tid < TJ) {
    int j = j0 + tid;
    jv[tid] = (j < n) ? make_float2(p[j], t[j])
                      : make_float2(INFINITY, INFINITY);  // pad: contributes 0
  }

  float pi[IPT], ti[IPT];
#pragma unroll
  for (int m = 0; m < IPT; ++m) {
    int i  = i0 + tid + m * BLK;
    int ic = i < n ? i : 0;           // clamped load, then neutralize via INF
    float pv = p[ic], tv = t[ic];
    pi[m] = (i < n) ? pv : INFINITY;
    ti[m] = (i < n) ? tv : INFINITY;
  }
  __syncthreads();

  int acc[IPT] = {};
  const float4* jv4 = reinterpret_cast<const float4*>(jv);
#pragma unroll
  for (int k2 = 0; k2 < TJ / 2; ++k2) {
    float4 w = jv4[k2];   // wave-uniform broadcast, ds_read_b128: j and j+1
#pragma unroll
    for (int m = 0; m < IPT; ++m) {
      acc[m] += (int)((pi[m] < w.x) != (ti[m] < w.y));
      acc[m] += (int)((pi[m] < w.z) != (ti[m] < w.w));
    }
  }

  int sum = 0;
#pragma unroll
  for (int m = 0; m < IPT; ++m) sum += acc[m];

  // 64-lane wave reduce, then cross-wave via LDS
  for (int off = 32; off > 0; off >>= 1)
    sum += __shfl_down(sum, off, 64);
  __shared__ int wsum[BLK / 64];
  if ((tid & 63) == 0) wsum[tid >> 6] = sum;
  __syncthreads();
  if (tid == 0) {
    int s = 0;
#pragma unroll
    for (int w = 0; w < BLK / 64; ++w) s += wsum[w];
    partial[blockIdx.y * gridDim.x + blockIdx.x] = s;
  }
}

__global__ __launch_bounds__(256) void ktau_final(
    const int* __restrict__ partial, int nparts,
    float* __restrict__ out, int n) {
  const int tid = threadIdx.x;
  long long sum = 0;
  for (int idx = tid; idx < nparts; idx += 256) sum += partial[idx];
  for (int off = 32; off > 0; off >>= 1)
    sum += __shfl_down(sum, off, 64);
  __shared__ long long wsum[4];
  if ((tid & 63) == 0) wsum[tid >> 6] = sum;
  __syncthreads();
  if (tid == 0) {
    long long disc = wsum[0] + wsum[1] + wsum[2] + wsum[3];
    double nn = (double)n * (double)(n - 1);
    double S = nn - 2.0 * (double)disc;   // diagonal contributes 0
    out[0] = (float)(1.0 - S / nn);
  }
}

extern "C" void kernel_launch(void* const* d_in, const int* in_sizes, int n_in,
                              void* d_out, int out_size, void* d_ws, size_t ws_size,
                              hipStream_t stream) {
  const float* p = (const float*)d_in[0];
  const float* t = (const float*)d_in[1];
  float* out = (float*)d_out;
  int* partial = (int*)d_ws;
  const int n = in_sizes[0];

  const int gx = (n + TI - 1) / TI;   // 4
  const int gy = (n + TJ - 1) / TJ;   // 256
  dim3 grid(gx, gy);

  ktau_pairs<<<grid, BLK, 0, stream>>>(p, t, partial, n);
  ktau_final<<<1, 256, 0, stream>>>(partial, gx * gy, out, n);
}